// Round 1
// baseline (2018.191 us; speedup 1.0000x reference)
//
#include <hip/hip_runtime.h>

#define H 64

// order-preserving float <-> uint encoding for atomicMax on floats
__device__ __forceinline__ unsigned enc_f(float f) {
    unsigned u = __float_as_uint(f);
    return (u & 0x80000000u) ? ~u : (u | 0x80000000u);
}
__device__ __forceinline__ float dec_f(unsigned u) {
    return (u & 0x80000000u) ? __uint_as_float(u & 0x7fffffffu) : __uint_as_float(~u);
}

__global__ void fill_zero(float* __restrict__ p, int n) {
    int i = blockIdx.x * blockDim.x + threadIdx.x;
    int stride = gridDim.x * blockDim.x;
    for (; i < n; i += stride) p[i] = 0.f;
}

// v1 = Ws @ a_s, v2 = Wd @ a_d   (each 64 floats; 1 block x 64 threads)
__global__ void wvec2_kernel(const float* __restrict__ Ws, const float* __restrict__ as_,
                             const float* __restrict__ Wd, const float* __restrict__ ad_,
                             float* __restrict__ v1, float* __restrict__ v2) {
    int k = threadIdx.x;
    float s1 = 0.f, s2 = 0.f;
    for (int j = 0; j < H; ++j) {
        s1 += Ws[k * H + j] * as_[j];
        s2 += Wd[k * H + j] * ad_[j];
    }
    v1[k] = s1;
    v2[k] = s2;
}

// out[n] = dot(x[n,:], v)  — one wave per row
__global__ void dot_kernel(const float* __restrict__ x, const float* __restrict__ v,
                           float* __restrict__ out, int n) {
    int wid = (int)((blockIdx.x * blockDim.x + threadIdx.x) >> 6);
    int lane = threadIdx.x & 63;
    if (wid >= n) return;
    float p = x[(size_t)wid * H + lane] * v[lane];
#pragma unroll
    for (int off = 32; off; off >>= 1) p += __shfl_xor(p, off);
    if (lane == 0) out[wid] = p;
}

// hs = x @ W   (x: n x 64, W: 64 x 64 row-major). One wave per row, W in LDS.
__global__ void gemm_hs(const float* __restrict__ x, const float* __restrict__ W,
                        float* __restrict__ hs, int n) {
    __shared__ float Wl[H * H];
    int t = threadIdx.x;
    for (int i = t; i < H * H; i += 256) Wl[i] = W[i];
    __syncthreads();
    int row = blockIdx.x * 4 + (t >> 6);
    int lane = t & 63;
    if (row >= n) return;
    float xr = x[(size_t)row * H + lane];
    float acc = 0.f;
#pragma unroll
    for (int k = 0; k < H; ++k) {
        acc += __shfl(xr, k) * Wl[k * H + lane];
    }
    hs[(size_t)row * H + lane] = acc;
}

// per-edge score = leaky_relu(ssrc[src] + sdst[dst]); store; segment max via atomicMax
__global__ void score_kernel(const int* __restrict__ src, const int* __restrict__ dst,
                             const float* __restrict__ ssrc, const float* __restrict__ sdst,
                             float* __restrict__ escore, unsigned* __restrict__ menc, int ne) {
    int e = blockIdx.x * blockDim.x + threadIdx.x;
    if (e >= ne) return;
    float sc = ssrc[src[e]] + sdst[dst[e]];
    sc = sc > 0.f ? sc : 0.2f * sc;
    escore[e] = sc;
    atomicMax(menc + dst[e], enc_f(sc));
}

// per-edge (one wave per edge): ev = exp(score - m[dst]); ssum[dst] += ev; acc[dst,:] += ev*hs[src,:]
__global__ void aggregate_kernel(const int* __restrict__ src, const int* __restrict__ dst,
                                 const float* __restrict__ escore, const unsigned* __restrict__ menc,
                                 const float* __restrict__ hs, float* __restrict__ acc,
                                 float* __restrict__ ssum, int ne) {
    int lane = threadIdx.x & 63;
    int wid = (int)((blockIdx.x * blockDim.x + threadIdx.x) >> 6);
    int nw = (int)((gridDim.x * blockDim.x) >> 6);
    for (int e = wid; e < ne; e += nw) {
        int s = src[e], d = dst[e];
        float m = dec_f(menc[d]);
        float ev = __expf(escore[e] - m);
        if (lane == 0) atomicAdd(ssum + d, ev);
        float v = ev * hs[(size_t)s * H + lane];
        atomicAdd(acc + (size_t)d * H + lane, v);
    }
}

// out[n,c] = relu(acc[n,c]/(ssum[n]+1e-16) + b[c])   in place on acc
__global__ void finalize_kernel(float* __restrict__ acc, const float* __restrict__ ssum,
                                const float* __restrict__ b, int total) {
    int i = blockIdx.x * blockDim.x + threadIdx.x;
    if (i >= total) return;
    int node = i >> 6, c = i & 63;
    float v = acc[i] / (ssum[node] + 1e-16f) + b[c];
    acc[i] = v > 0.f ? v : 0.f;
}

// out[n] = relu(xn[n,:] @ W1 + b1) @ w2 + b2   (W1: 64x32, w2: 32)
__global__ void mlp_kernel(const float* __restrict__ xn, const float* __restrict__ w1,
                           const float* __restrict__ b1, const float* __restrict__ w2,
                           const float* __restrict__ b2, float* __restrict__ out, int n) {
    __shared__ float W1[H * 32];
    __shared__ float W2[32];
    int t = threadIdx.x;
    for (int i = t; i < H * 32; i += 256) W1[i] = w1[i];
    if (t < 32) W2[t] = w2[t];
    __syncthreads();
    int c = t & 31;
    int row = blockIdx.x * 8 + (t >> 5);
    if (row >= n) return;
    float s = 0.f;
#pragma unroll
    for (int k = 0; k < H; ++k) s += xn[(size_t)row * H + k] * W1[k * 32 + c];
    s += b1[c];
    s = s > 0.f ? s : 0.f;
    float p = s * W2[c];
#pragma unroll
    for (int off = 16; off; off >>= 1) p += __shfl_xor(p, off);
    if (c == 0) out[row] = p + b2[0];
}

extern "C" void kernel_launch(void* const* d_in, const int* in_sizes, int n_in,
                              void* d_out, int out_size, void* d_ws, size_t ws_size,
                              hipStream_t stream) {
    const float* x_inst  = (const float*)d_in[0];
    const float* x_net   = (const float*)d_in[1];
    const int*   e_i2n   = (const int*)d_in[2];
    const int*   e_n2i   = (const int*)d_in[3];
    const float* W_src   = (const float*)d_in[4];
    const float* W_dst   = (const float*)d_in[5];
    const float* att_src = (const float*)d_in[6];
    const float* att_dst = (const float*)d_in[7];
    const float* bias_g  = (const float*)d_in[8];
    const float* lin1_w  = (const float*)d_in[9];
    const float* lin1_b  = (const float*)d_in[10];
    const float* lin2_w  = (const float*)d_in[11];
    const float* lin2_b  = (const float*)d_in[12];

    const int n_inst = in_sizes[0] / H;
    const int n_net  = in_sizes[1] / H;
    const int ne     = in_sizes[2] / 2;
    const int nmax   = n_inst > n_net ? n_inst : n_net;

    float* ws = (float*)d_ws;
    size_t off = 0;
    auto alloc = [&](size_t nelem) { float* p = ws + off; off += nelem; return p; };
    float* xnA    = alloc((size_t)n_net * H);   // layer0 net output
    float* xiA    = alloc((size_t)n_inst * H);  // layer0 inst output
    float* xnB    = alloc((size_t)n_net * H);   // layer1 net output
    float* hs     = alloc((size_t)nmax * H);
    float* ssrc   = alloc(nmax);
    float* sdst   = alloc(nmax);
    unsigned* menc = (unsigned*)alloc(nmax);
    float* ssum   = alloc(nmax);
    float* escore = alloc(ne);
    float* v1     = alloc(H);
    float* v2     = alloc(H);
    (void)ws_size;

    auto relation = [&](const float* xsrc, int nsrc, const float* xdst, int ndst,
                        const int* esrc, const int* edst, int li, int ri, float* outbuf) {
        const float* Ws  = W_src + (size_t)(li * 2 + ri) * H * H;
        const float* Wd  = W_dst + (size_t)(li * 2 + ri) * H * H;
        const float* as_ = att_src + (size_t)(li * 2 + ri) * H;
        const float* ad_ = att_dst + (size_t)(li * 2 + ri) * H;
        const float* bg  = bias_g + (size_t)(li * 2 + ri) * H;

        wvec2_kernel<<<1, 64, 0, stream>>>(Ws, as_, Wd, ad_, v1, v2);
        dot_kernel<<<(nsrc + 3) / 4, 256, 0, stream>>>(xsrc, v1, ssrc, nsrc);
        dot_kernel<<<(ndst + 3) / 4, 256, 0, stream>>>(xdst, v2, sdst, ndst);
        gemm_hs<<<(nsrc + 3) / 4, 256, 0, stream>>>(xsrc, Ws, hs, nsrc);

        fill_zero<<<256, 256, 0, stream>>>((float*)menc, ndst);
        score_kernel<<<(ne + 255) / 256, 256, 0, stream>>>(esrc, edst, ssrc, sdst, escore, menc, ne);

        fill_zero<<<256, 256, 0, stream>>>(ssum, ndst);
        fill_zero<<<2048, 256, 0, stream>>>(outbuf, ndst * H);
        aggregate_kernel<<<4096, 256, 0, stream>>>(esrc, edst, escore, menc, hs, outbuf, ssum, ne);
        finalize_kernel<<<(ndst * H + 255) / 256, 256, 0, stream>>>(outbuf, ssum, bg, ndst * H);
    };

    // layer 0 (reads original inputs for both relations)
    relation(x_inst, n_inst, x_net, n_net, e_i2n, e_i2n + ne, 0, 0, xnA);
    relation(x_net, n_net, x_inst, n_inst, e_n2i, e_n2i + ne, 0, 1, xiA);
    // layer 1: only the net-side output feeds the head; inst-side (l=1,r=1) is dead code
    relation(xiA, n_inst, xnA, n_net, e_i2n, e_i2n + ne, 1, 0, xnB);

    // head: out = relu(xnB @ W1 + b1) @ w2 + b2
    mlp_kernel<<<(n_net + 7) / 8, 256, 0, stream>>>(xnB, lin1_w, lin1_b, lin2_w, lin2_b,
                                                    (float*)d_out, n_net);
}

// Round 2
// 1333.121 us; speedup vs baseline: 1.5139x; 1.5139x over previous
//
#include <hip/hip_runtime.h>

#define H 64

__global__ void fill_zero(float* __restrict__ p, int n) {
    int i = blockIdx.x * blockDim.x + threadIdx.x;
    int stride = gridDim.x * blockDim.x;
    for (; i < n; i += stride) p[i] = 0.f;
}

// v1 = Ws @ a_s, v2 = Wd @ a_d   (each 64 floats; 1 block x 64 threads)
__global__ void wvec2_kernel(const float* __restrict__ Ws, const float* __restrict__ as_,
                             const float* __restrict__ Wd, const float* __restrict__ ad_,
                             float* __restrict__ v1, float* __restrict__ v2) {
    int k = threadIdx.x;
    float s1 = 0.f, s2 = 0.f;
    for (int j = 0; j < H; ++j) {
        s1 += Ws[k * H + j] * as_[j];
        s2 += Wd[k * H + j] * ad_[j];
    }
    v1[k] = s1;
    v2[k] = s2;
}

// out[n] = dot(x[n,:], v)  — one wave per row
__global__ void dot_kernel(const float* __restrict__ x, const float* __restrict__ v,
                           float* __restrict__ out, int n) {
    int wid = (int)((blockIdx.x * blockDim.x + threadIdx.x) >> 6);
    int lane = threadIdx.x & 63;
    if (wid >= n) return;
    float p = x[(size_t)wid * H + lane] * v[lane];
#pragma unroll
    for (int off = 32; off; off >>= 1) p += __shfl_xor(p, off);
    if (lane == 0) out[wid] = p;
}

// hs = x @ W   (x: n x 64, W: 64 x 64 row-major). One wave per row, W in LDS.
__global__ void gemm_hs(const float* __restrict__ x, const float* __restrict__ W,
                        float* __restrict__ hs, int n) {
    __shared__ float Wl[H * H];
    int t = threadIdx.x;
    for (int i = t; i < H * H; i += 256) Wl[i] = W[i];
    __syncthreads();
    int row = blockIdx.x * 4 + (t >> 6);
    int lane = t & 63;
    if (row >= n) return;
    float xr = x[(size_t)row * H + lane];
    float acc = 0.f;
#pragma unroll
    for (int k = 0; k < H; ++k) {
        acc += __shfl(xr, k) * Wl[k * H + lane];
    }
    hs[(size_t)row * H + lane] = acc;
}

// ---- CSR build ----
__global__ void hist_kernel(const int* __restrict__ dst, int* __restrict__ count, int ne) {
    int i = blockIdx.x * blockDim.x + threadIdx.x;
    int stride = gridDim.x * blockDim.x;
    for (; i < ne; i += stride) atomicAdd(&count[dst[i]], 1);
}

// per-block exclusive scan of count -> rowptr, block totals -> bsum
__global__ void scan_block(const int* __restrict__ count, int* __restrict__ excl,
                           int* __restrict__ bsum, int n) {
    __shared__ int sm[256];
    int t = threadIdx.x;
    int i = blockIdx.x * 256 + t;
    int c = i < n ? count[i] : 0;
    sm[t] = c;
    __syncthreads();
    for (int off = 1; off < 256; off <<= 1) {
        int v = t >= off ? sm[t - off] : 0;
        __syncthreads();
        sm[t] += v;
        __syncthreads();
    }
    if (i < n) excl[i] = sm[t] - c;
    if (t == 255) bsum[blockIdx.x] = sm[255];
}

// in-place exclusive scan of block sums (nb <= 1024), single block of 1024
__global__ void scan_bsum(int* __restrict__ bsum, int nb) {
    __shared__ int sm[1024];
    int t = threadIdx.x;
    int c = t < nb ? bsum[t] : 0;
    sm[t] = c;
    __syncthreads();
    for (int off = 1; off < 1024; off <<= 1) {
        int v = t >= off ? sm[t - off] : 0;
        __syncthreads();
        sm[t] += v;
        __syncthreads();
    }
    if (t < nb) bsum[t] = sm[t] - c;
}

// rowptr[i] += bsum[i/256]; cursor[i] = rowptr[i]; rowptr[n] = ne
__global__ void add_offsets(int* __restrict__ rowptr, const int* __restrict__ bsum,
                            int* __restrict__ cursor, int n, int ne) {
    int i = blockIdx.x * blockDim.x + threadIdx.x;
    if (i < n) {
        int r = rowptr[i] + bsum[i >> 8];
        rowptr[i] = r;
        cursor[i] = r;
    }
    if (i == n) rowptr[n] = ne;
}

__global__ void scatter_kernel(const int* __restrict__ src, const int* __restrict__ dst,
                               int* __restrict__ cursor, int* __restrict__ srcs_sorted, int ne) {
    int i = blockIdx.x * blockDim.x + threadIdx.x;
    int stride = gridDim.x * blockDim.x;
    for (; i < ne; i += stride) {
        int pos = atomicAdd(&cursor[dst[i]], 1);
        srcs_sorted[pos] = src[i];
    }
}

// ---- fused per-dst-node GAT aggregation with online softmax ----
// one wave per dst node; lane = channel
__global__ void gat_node_kernel(const int* __restrict__ rowptr, const int* __restrict__ srcs,
                                const float* __restrict__ ssrc, const float* __restrict__ xdst,
                                const float* __restrict__ v2, const float* __restrict__ hs,
                                const float* __restrict__ bias, float* __restrict__ out, int ndst) {
    int wid = (int)((blockIdx.x * blockDim.x + threadIdx.x) >> 6);
    int lane = threadIdx.x & 63;
    if (wid >= ndst) return;

    // sdst = dot(xdst[wid,:], v2), broadcast to all lanes
    float p = xdst[(size_t)wid * H + lane] * v2[lane];
#pragma unroll
    for (int off = 32; off; off >>= 1) p += __shfl_xor(p, off);
    float sdst = p;

    int beg = rowptr[wid], end = rowptr[wid + 1];
    float m = -3.4e38f, l = 0.f, acc = 0.f;
    for (int base = beg; base < end; base += 64) {
        int cnt = end - base; if (cnt > 64) cnt = 64;
        int idx = base + lane;
        int s_l = idx < end ? srcs[idx] : 0;
        float sc_l = idx < end ? ssrc[s_l] : 0.f;
        sc_l += sdst;
        sc_l = sc_l > 0.f ? sc_l : 0.2f * sc_l;
        for (int j = 0; j < cnt; ++j) {
            int s = __shfl(s_l, j);
            float sc = __shfl(sc_l, j);
            float mn = fmaxf(m, sc);
            float scale = __expf(m - mn);   // m=-inf first iter -> 0
            float ev = __expf(sc - mn);
            l = l * scale + ev;
            acc = acc * scale + ev * hs[(size_t)s * H + lane];
            m = mn;
        }
    }
    float v = acc / (l + 1e-16f) + bias[lane];
    out[(size_t)wid * H + lane] = v > 0.f ? v : 0.f;
}

// out[n] = relu(xn[n,:] @ W1 + b1) @ w2 + b2   (W1: 64x32, w2: 32)
__global__ void mlp_kernel(const float* __restrict__ xn, const float* __restrict__ w1,
                           const float* __restrict__ b1, const float* __restrict__ w2,
                           const float* __restrict__ b2, float* __restrict__ out, int n) {
    __shared__ float W1[H * 32];
    __shared__ float W2[32];
    int t = threadIdx.x;
    for (int i = t; i < H * 32; i += 256) W1[i] = w1[i];
    if (t < 32) W2[t] = w2[t];
    __syncthreads();
    int c = t & 31;
    int row = blockIdx.x * 8 + (t >> 5);
    if (row >= n) return;
    float s = 0.f;
#pragma unroll
    for (int k = 0; k < H; ++k) s += xn[(size_t)row * H + k] * W1[k * 32 + c];
    s += b1[c];
    s = s > 0.f ? s : 0.f;
    float p = s * W2[c];
#pragma unroll
    for (int off = 16; off; off >>= 1) p += __shfl_xor(p, off);
    if (c == 0) out[row] = p + b2[0];
}

extern "C" void kernel_launch(void* const* d_in, const int* in_sizes, int n_in,
                              void* d_out, int out_size, void* d_ws, size_t ws_size,
                              hipStream_t stream) {
    const float* x_inst  = (const float*)d_in[0];
    const float* x_net   = (const float*)d_in[1];
    const int*   e_i2n   = (const int*)d_in[2];
    const int*   e_n2i   = (const int*)d_in[3];
    const float* W_src   = (const float*)d_in[4];
    const float* W_dst   = (const float*)d_in[5];
    const float* att_src = (const float*)d_in[6];
    const float* att_dst = (const float*)d_in[7];
    const float* bias_g  = (const float*)d_in[8];
    const float* lin1_w  = (const float*)d_in[9];
    const float* lin1_b  = (const float*)d_in[10];
    const float* lin2_w  = (const float*)d_in[11];
    const float* lin2_b  = (const float*)d_in[12];

    const int n_inst = in_sizes[0] / H;
    const int n_net  = in_sizes[1] / H;
    const int ne     = in_sizes[2] / 2;
    const int nmax   = n_inst > n_net ? n_inst : n_net;

    float* ws = (float*)d_ws;
    size_t off = 0;
    auto alloc = [&](size_t nelem) { float* p = ws + off; off += nelem; return p; };
    float* xnA    = alloc((size_t)n_net * H);   // layer0 net output
    float* xiA    = alloc((size_t)n_inst * H);  // layer0 inst output
    float* xnB    = alloc((size_t)n_net * H);   // layer1 net output
    float* hs     = alloc((size_t)nmax * H);
    float* ssrc   = alloc(nmax);
    int*   rowptr = (int*)alloc(nmax + 1);
    int*   cursor = (int*)alloc(nmax);
    int*   srcs   = (int*)alloc(ne);
    int*   bsum   = (int*)alloc(1024);
    float* v1     = alloc(H);
    float* v2     = alloc(H);
    (void)ws_size;

    auto relation = [&](const float* xsrc, int nsrc, const float* xdst, int ndst,
                        const int* esrc, const int* edst, int li, int ri, float* outbuf) {
        const float* Ws  = W_src + (size_t)(li * 2 + ri) * H * H;
        const float* Wd  = W_dst + (size_t)(li * 2 + ri) * H * H;
        const float* as_ = att_src + (size_t)(li * 2 + ri) * H;
        const float* ad_ = att_dst + (size_t)(li * 2 + ri) * H;
        const float* bg  = bias_g + (size_t)(li * 2 + ri) * H;

        // projections
        wvec2_kernel<<<1, 64, 0, stream>>>(Ws, as_, Wd, ad_, v1, v2);
        dot_kernel<<<(nsrc + 3) / 4, 256, 0, stream>>>(xsrc, v1, ssrc, nsrc);
        gemm_hs<<<(nsrc + 3) / 4, 256, 0, stream>>>(xsrc, Ws, hs, nsrc);

        // CSR build: count -> scan -> scatter
        fill_zero<<<128, 256, 0, stream>>>((float*)cursor, ndst);  // cursor doubles as count
        hist_kernel<<<2048, 256, 0, stream>>>(edst, cursor, ne);
        int nb = (ndst + 255) / 256;
        scan_block<<<nb, 256, 0, stream>>>(cursor, rowptr, bsum, ndst);
        scan_bsum<<<1, 1024, 0, stream>>>(bsum, nb);
        add_offsets<<<(ndst + 256) / 256, 256, 0, stream>>>(rowptr, bsum, cursor, ndst, ne);
        scatter_kernel<<<2048, 256, 0, stream>>>(esrc, edst, cursor, srcs, ne);

        // fused aggregation + softmax + bias + relu
        gat_node_kernel<<<(ndst + 3) / 4, 256, 0, stream>>>(rowptr, srcs, ssrc, xdst, v2,
                                                            hs, bg, outbuf, ndst);
    };

    // layer 0 (reads original inputs for both relations)
    relation(x_inst, n_inst, x_net, n_net, e_i2n, e_i2n + ne, 0, 0, xnA);
    relation(x_net, n_net, x_inst, n_inst, e_n2i, e_n2i + ne, 0, 1, xiA);
    // layer 1: only the net-side output feeds the head; inst-side (l=1,r=1) is dead code
    relation(xiA, n_inst, xnA, n_net, e_i2n, e_i2n + ne, 1, 0, xnB);

    // head: out = relu(xnB @ W1 + b1) @ w2 + b2
    mlp_kernel<<<(n_net + 7) / 8, 256, 0, stream>>>(xnB, lin1_w, lin1_b, lin2_w, lin2_b,
                                                    (float*)d_out, n_net);
}

// Round 3
// 1127.977 us; speedup vs baseline: 1.7892x; 1.1819x over previous
//
#include <hip/hip_runtime.h>

#define H 64

__global__ void fill_zero(float* __restrict__ p, int n) {
    int i = blockIdx.x * blockDim.x + threadIdx.x;
    int stride = gridDim.x * blockDim.x;
    for (; i < n; i += stride) p[i] = 0.f;
}

// v2 = Wd @ a_d   (64 floats; 1 block x 64 threads)
__global__ void wvec_kernel(const float* __restrict__ Wd, const float* __restrict__ ad_,
                            float* __restrict__ v2) {
    int k = threadIdx.x;
    float s2 = 0.f;
    for (int j = 0; j < H; ++j) s2 += Wd[k * H + j] * ad_[j];
    v2[k] = s2;
}

// hs = x @ W ; ssrc = hs . a_s   (one wave per row, W in LDS)
__global__ void gemm_hs_fused(const float* __restrict__ x, const float* __restrict__ W,
                              const float* __restrict__ as_, float* __restrict__ hs,
                              float* __restrict__ ssrc, int n) {
    __shared__ float Wl[H * H];
    int t = threadIdx.x;
    for (int i = t; i < H * H; i += 256) Wl[i] = W[i];
    __syncthreads();
    int row = blockIdx.x * 4 + (t >> 6);
    int lane = t & 63;
    if (row >= n) return;
    float xr = x[(size_t)row * H + lane];
    float acc = 0.f;
#pragma unroll
    for (int k = 0; k < H; ++k) {
        acc += __shfl(xr, k) * Wl[k * H + lane];
    }
    hs[(size_t)row * H + lane] = acc;
    // ssrc = dot(hs_row, a_s)
    float p = acc * as_[lane];
#pragma unroll
    for (int off = 32; off; off >>= 1) p += __shfl_xor(p, off);
    if (lane == 0) ssrc[row] = p;
}

// ---- CSR build ----
__global__ void hist_kernel(const int* __restrict__ dst, int* __restrict__ count, int ne) {
    int i = blockIdx.x * blockDim.x + threadIdx.x;
    int stride = gridDim.x * blockDim.x;
    for (; i < ne; i += stride) atomicAdd(&count[dst[i]], 1);
}

__global__ void scan_block(const int* __restrict__ count, int* __restrict__ excl,
                           int* __restrict__ bsum, int n) {
    __shared__ int sm[256];
    int t = threadIdx.x;
    int i = blockIdx.x * 256 + t;
    int c = i < n ? count[i] : 0;
    sm[t] = c;
    __syncthreads();
    for (int off = 1; off < 256; off <<= 1) {
        int v = t >= off ? sm[t - off] : 0;
        __syncthreads();
        sm[t] += v;
        __syncthreads();
    }
    if (i < n) excl[i] = sm[t] - c;
    if (t == 255) bsum[blockIdx.x] = sm[255];
}

__global__ void scan_bsum(int* __restrict__ bsum, int nb) {
    __shared__ int sm[1024];
    int t = threadIdx.x;
    int c = t < nb ? bsum[t] : 0;
    sm[t] = c;
    __syncthreads();
    for (int off = 1; off < 1024; off <<= 1) {
        int v = t >= off ? sm[t - off] : 0;
        __syncthreads();
        sm[t] += v;
        __syncthreads();
    }
    if (t < nb) bsum[t] = sm[t] - c;
}

__global__ void add_offsets(int* __restrict__ rowptr, const int* __restrict__ bsum,
                            int* __restrict__ cursor, int n, int ne) {
    int i = blockIdx.x * blockDim.x + threadIdx.x;
    if (i < n) {
        int r = rowptr[i] + bsum[i >> 8];
        rowptr[i] = r;
        cursor[i] = r;
    }
    if (i == n) rowptr[n] = ne;
}

__global__ void scatter_kernel(const int* __restrict__ src, const int* __restrict__ dst,
                               int* __restrict__ cursor, int* __restrict__ srcs_sorted, int ne) {
    int i = blockIdx.x * blockDim.x + threadIdx.x;
    int stride = gridDim.x * blockDim.x;
    for (; i < ne; i += stride) {
        int pos = atomicAdd(&cursor[dst[i]], 1);
        __builtin_nontemporal_store(src[i], &srcs_sorted[pos]);
    }
}

// ---- fused per-dst-node GAT aggregation with online softmax ----
__global__ void gat_node_kernel(const int* __restrict__ rowptr, const int* __restrict__ srcs,
                                const float* __restrict__ ssrc, const float* __restrict__ xdst,
                                const float* __restrict__ v2, const float* __restrict__ hs,
                                const float* __restrict__ bias, float* __restrict__ out, int ndst) {
    int wid = (int)((blockIdx.x * blockDim.x + threadIdx.x) >> 6);
    int lane = threadIdx.x & 63;
    if (wid >= ndst) return;

    float p = xdst[(size_t)wid * H + lane] * v2[lane];
#pragma unroll
    for (int off = 32; off; off >>= 1) p += __shfl_xor(p, off);
    float sdst = p;

    int beg = rowptr[wid], end = rowptr[wid + 1];
    float m = -3.4e38f, l = 0.f, acc = 0.f;
    for (int base = beg; base < end; base += 64) {
        int cnt = end - base; if (cnt > 64) cnt = 64;
        int idx = base + lane;
        int s_l = idx < end ? srcs[idx] : 0;
        float sc_l = idx < end ? ssrc[s_l] : 0.f;
        sc_l += sdst;
        sc_l = sc_l > 0.f ? sc_l : 0.2f * sc_l;
        for (int j = 0; j < cnt; ++j) {
            int s = __shfl(s_l, j);
            float sc = __shfl(sc_l, j);
            float mn = fmaxf(m, sc);
            float scale = __expf(m - mn);
            float ev = __expf(sc - mn);
            l = l * scale + ev;
            acc = acc * scale + ev * hs[(size_t)s * H + lane];
            m = mn;
        }
    }
    float v = acc / (l + 1e-16f) + bias[lane];
    out[(size_t)wid * H + lane] = v > 0.f ? v : 0.f;
}

// ---- final relation: GAT aggregation + fused MLP head ----
// out[node] = relu(relu(gat_row) @ W1 + b1) @ w2 + b2
__global__ void gat_node_mlp_kernel(const int* __restrict__ rowptr, const int* __restrict__ srcs,
                                    const float* __restrict__ ssrc, const float* __restrict__ xdst,
                                    const float* __restrict__ v2, const float* __restrict__ hs,
                                    const float* __restrict__ bias,
                                    const float* __restrict__ w1, const float* __restrict__ b1,
                                    const float* __restrict__ w2, const float* __restrict__ b2,
                                    float* __restrict__ out, int ndst) {
    __shared__ float W1[H * 32];
    __shared__ float W2[32];
    __shared__ float B1[32];
    {
        int t = threadIdx.x;
        for (int i = t; i < H * 32; i += 256) W1[i] = w1[i];
        if (t < 32) { W2[t] = w2[t]; B1[t] = b1[t]; }
        __syncthreads();
    }
    int wid = (int)((blockIdx.x * blockDim.x + threadIdx.x) >> 6);
    int lane = threadIdx.x & 63;
    if (wid >= ndst) return;

    float p = xdst[(size_t)wid * H + lane] * v2[lane];
#pragma unroll
    for (int off = 32; off; off >>= 1) p += __shfl_xor(p, off);
    float sdst = p;

    int beg = rowptr[wid], end = rowptr[wid + 1];
    float m = -3.4e38f, l = 0.f, acc = 0.f;
    for (int base = beg; base < end; base += 64) {
        int cnt = end - base; if (cnt > 64) cnt = 64;
        int idx = base + lane;
        int s_l = idx < end ? srcs[idx] : 0;
        float sc_l = idx < end ? ssrc[s_l] : 0.f;
        sc_l += sdst;
        sc_l = sc_l > 0.f ? sc_l : 0.2f * sc_l;
        for (int j = 0; j < cnt; ++j) {
            int s = __shfl(s_l, j);
            float sc = __shfl(sc_l, j);
            float mn = fmaxf(m, sc);
            float scale = __expf(m - mn);
            float ev = __expf(sc - mn);
            l = l * scale + ev;
            acc = acc * scale + ev * hs[(size_t)s * H + lane];
            m = mn;
        }
    }
    float v = acc / (l + 1e-16f) + bias[lane];
    v = v > 0.f ? v : 0.f;   // xn row value for channel `lane`

    // h[c] = relu(sum_k v_k * W1[k][c] + b1[c]);  scalar = h @ w2 + b2
    int c = lane & 31;
    float s = 0.f;
#pragma unroll
    for (int k = 0; k < H; ++k) s += __shfl(v, k) * W1[k * 32 + c];
    s += B1[c];
    s = s > 0.f ? s : 0.f;
    float q = s * W2[c];
#pragma unroll
    for (int off = 16; off; off >>= 1) q += __shfl_xor(q, off);
    if (lane == 0) out[wid] = q + b2[0];
}

extern "C" void kernel_launch(void* const* d_in, const int* in_sizes, int n_in,
                              void* d_out, int out_size, void* d_ws, size_t ws_size,
                              hipStream_t stream) {
    const float* x_inst  = (const float*)d_in[0];
    const float* x_net   = (const float*)d_in[1];
    const int*   e_i2n   = (const int*)d_in[2];
    const int*   e_n2i   = (const int*)d_in[3];
    const float* W_src   = (const float*)d_in[4];
    const float* W_dst   = (const float*)d_in[5];
    const float* att_src = (const float*)d_in[6];
    const float* att_dst = (const float*)d_in[7];
    const float* bias_g  = (const float*)d_in[8];
    const float* lin1_w  = (const float*)d_in[9];
    const float* lin1_b  = (const float*)d_in[10];
    const float* lin2_w  = (const float*)d_in[11];
    const float* lin2_b  = (const float*)d_in[12];

    const int n_inst = in_sizes[0] / H;
    const int n_net  = in_sizes[1] / H;
    const int ne     = in_sizes[2] / 2;
    const int nmax   = n_inst > n_net ? n_inst : n_net;

    float* ws = (float*)d_ws;
    size_t off = 0;
    auto alloc = [&](size_t nelem) { float* p = ws + off; off += nelem; return p; };
    float* xnA     = alloc((size_t)n_net * H);
    float* xiA     = alloc((size_t)n_inst * H);
    float* hs      = alloc((size_t)nmax * H);
    float* ssrc    = alloc(nmax);
    int*   rp_i2n  = (int*)alloc(nmax + 1);
    int*   sr_i2n  = (int*)alloc(ne);
    int*   rp_n2i  = (int*)alloc(nmax + 1);
    int*   sr_n2i  = (int*)alloc(ne);
    int*   cursor  = (int*)alloc(nmax);
    int*   bsum    = (int*)alloc(1024);
    float* v2      = alloc(H);
    (void)ws_size;

    auto build_csr = [&](const int* esrc, const int* edst, int ndst,
                         int* rowptr, int* srcs) {
        fill_zero<<<128, 256, 0, stream>>>((float*)cursor, ndst);
        hist_kernel<<<2048, 256, 0, stream>>>(edst, cursor, ne);
        int nb = (ndst + 255) / 256;
        scan_block<<<nb, 256, 0, stream>>>(cursor, rowptr, bsum, ndst);
        scan_bsum<<<1, 1024, 0, stream>>>(bsum, nb);
        add_offsets<<<(ndst + 256) / 256, 256, 0, stream>>>(rowptr, bsum, cursor, ndst, ne);
        scatter_kernel<<<2048, 256, 0, stream>>>(esrc, edst, cursor, srcs, ne);
    };

    // CSR for each edge list, built once
    build_csr(e_i2n, e_i2n + ne, n_net, rp_i2n, sr_i2n);
    build_csr(e_n2i, e_n2i + ne, n_inst, rp_n2i, sr_n2i);

    auto proj = [&](const float* xsrc, int nsrc, int li, int ri) {
        const float* Ws  = W_src + (size_t)(li * 2 + ri) * H * H;
        const float* Wd  = W_dst + (size_t)(li * 2 + ri) * H * H;
        const float* as_ = att_src + (size_t)(li * 2 + ri) * H;
        const float* ad_ = att_dst + (size_t)(li * 2 + ri) * H;
        wvec_kernel<<<1, 64, 0, stream>>>(Wd, ad_, v2);
        gemm_hs_fused<<<(nsrc + 3) / 4, 256, 0, stream>>>(xsrc, Ws, as_, hs, ssrc, nsrc);
    };

    // layer 0, relation 0: inst -> net
    proj(x_inst, n_inst, 0, 0);
    gat_node_kernel<<<(n_net + 3) / 4, 256, 0, stream>>>(rp_i2n, sr_i2n, ssrc, x_net, v2,
                                                         hs, bias_g + 0 * H, xnA, n_net);
    // layer 0, relation 1: net -> inst
    proj(x_net, n_net, 0, 1);
    gat_node_kernel<<<(n_inst + 3) / 4, 256, 0, stream>>>(rp_n2i, sr_n2i, ssrc, x_inst, v2,
                                                          hs, bias_g + 1 * H, xiA, n_inst);
    // layer 1, relation 0: inst -> net, fused with MLP head (inst-side l1 is dead code)
    proj(xiA, n_inst, 1, 0);
    gat_node_mlp_kernel<<<(n_net + 3) / 4, 256, 0, stream>>>(rp_i2n, sr_i2n, ssrc, xnA, v2,
                                                             hs, bias_g + 2 * H,
                                                             lin1_w, lin1_b, lin2_w, lin2_b,
                                                             (float*)d_out, n_net);
}

// Round 4
// 1045.241 us; speedup vs baseline: 1.9308x; 1.0792x over previous
//
#include <hip/hip_runtime.h>

#define H 64

__global__ void fill_zero(float* __restrict__ p, int n) {
    int i = blockIdx.x * blockDim.x + threadIdx.x;
    int stride = gridDim.x * blockDim.x;
    for (; i < n; i += stride) p[i] = 0.f;
}

// v2 = Wd @ a_d   (64 floats; 1 block x 64 threads)
__global__ void wvec_kernel(const float* __restrict__ Wd, const float* __restrict__ ad_,
                            float* __restrict__ v2) {
    int k = threadIdx.x;
    float s2 = 0.f;
    for (int j = 0; j < H; ++j) s2 += Wd[k * H + j] * ad_[j];
    v2[k] = s2;
}

// hs = x @ W ; ssrc = hs . a_s   (one wave per row, W in LDS)
__global__ void gemm_hs_fused(const float* __restrict__ x, const float* __restrict__ W,
                              const float* __restrict__ as_, float* __restrict__ hs,
                              float* __restrict__ ssrc, int n) {
    __shared__ float Wl[H * H];
    int t = threadIdx.x;
    for (int i = t; i < H * H; i += 256) Wl[i] = W[i];
    __syncthreads();
    int row = blockIdx.x * 4 + (t >> 6);
    int lane = t & 63;
    if (row >= n) return;
    float xr = x[(size_t)row * H + lane];
    float acc = 0.f;
#pragma unroll
    for (int k = 0; k < H; ++k) {
        acc += __shfl(xr, k) * Wl[k * H + lane];
    }
    hs[(size_t)row * H + lane] = acc;
    float p = acc * as_[lane];
#pragma unroll
    for (int off = 32; off; off >>= 1) p += __shfl_xor(p, off);
    if (lane == 0) ssrc[row] = p;
}

// ---- CSR build (both edge lists in one pass for latency overlap) ----
__global__ void hist2_kernel(const int* __restrict__ dst1, const int* __restrict__ dst2,
                             int* __restrict__ cnt1, int* __restrict__ cnt2, int ne) {
    int i = blockIdx.x * blockDim.x + threadIdx.x;
    int stride = gridDim.x * blockDim.x;
    int total = 2 * ne;
    for (; i < total; i += stride) {
        if (i < ne) atomicAdd(&cnt1[dst1[i]], 1);
        else        atomicAdd(&cnt2[dst2[i - ne]], 1);
    }
}

__global__ void scan_block(const int* __restrict__ count, int* __restrict__ excl,
                           int* __restrict__ bsum, int n) {
    __shared__ int sm[256];
    int t = threadIdx.x;
    int i = blockIdx.x * 256 + t;
    int c = i < n ? count[i] : 0;
    sm[t] = c;
    __syncthreads();
    for (int off = 1; off < 256; off <<= 1) {
        int v = t >= off ? sm[t - off] : 0;
        __syncthreads();
        sm[t] += v;
        __syncthreads();
    }
    if (i < n) excl[i] = sm[t] - c;
    if (t == 255) bsum[blockIdx.x] = sm[255];
}

__global__ void scan_bsum(int* __restrict__ bsum, int nb) {
    __shared__ int sm[1024];
    int t = threadIdx.x;
    int c = t < nb ? bsum[t] : 0;
    sm[t] = c;
    __syncthreads();
    for (int off = 1; off < 1024; off <<= 1) {
        int v = t >= off ? sm[t - off] : 0;
        __syncthreads();
        sm[t] += v;
        __syncthreads();
    }
    if (t < nb) bsum[t] = sm[t] - c;
}

__global__ void add_offsets(int* __restrict__ rowptr, const int* __restrict__ bsum,
                            int* __restrict__ cursor, int n, int ne) {
    int i = blockIdx.x * blockDim.x + threadIdx.x;
    if (i < n) {
        int r = rowptr[i] + bsum[i >> 8];
        rowptr[i] = r;
        cursor[i] = r;
    }
    if (i == n) rowptr[n] = ne;
}

__global__ void scatter2_kernel(const int* __restrict__ src1, const int* __restrict__ dst1,
                                int* __restrict__ cur1, int* __restrict__ out1,
                                const int* __restrict__ src2, const int* __restrict__ dst2,
                                int* __restrict__ cur2, int* __restrict__ out2, int ne) {
    int i = blockIdx.x * blockDim.x + threadIdx.x;
    int stride = gridDim.x * blockDim.x;
    int total = 2 * ne;
    for (; i < total; i += stride) {
        if (i < ne) {
            int pos = atomicAdd(&cur1[dst1[i]], 1);
            __builtin_nontemporal_store(src1[i], &out1[pos]);
        } else {
            int j = i - ne;
            int pos = atomicAdd(&cur2[dst2[j]], 1);
            __builtin_nontemporal_store(src2[j], &out2[pos]);
        }
    }
}

// ---- fused per-dst-node GAT aggregation, two-phase softmax ----
// returns node output value for this lane's channel (device helper)
__device__ __forceinline__ float gat_aggregate(const int* __restrict__ rowptr,
                                               const int* __restrict__ srcs,
                                               const float* __restrict__ ssrc,
                                               const float* __restrict__ xdst,
                                               const float* __restrict__ v2,
                                               const float* __restrict__ hs,
                                               const float* __restrict__ bias,
                                               int wid, int lane) {
    // sdst = dot(xdst[wid,:], v2)
    float p = xdst[(size_t)wid * H + lane] * v2[lane];
#pragma unroll
    for (int off = 32; off; off >>= 1) p += __shfl_xor(p, off);
    float sdst = p;

    int beg = rowptr[wid], end = rowptr[wid + 1];
    int cnt = end - beg;
    float acc0 = 0.f, acc1 = 0.f, l;

    if (cnt <= 64) {
        bool valid = lane < cnt;
        int s_l = valid ? srcs[beg + lane] : 0;
        float sc = ssrc[s_l] + sdst;
        sc = sc > 0.f ? sc : 0.2f * sc;
        float mm = valid ? sc : -3.4e38f;
#pragma unroll
        for (int off = 32; off; off >>= 1) mm = fmaxf(mm, __shfl_xor(mm, off));
        float ev_l = valid ? __expf(sc - mm) : 0.f;
        float ll = ev_l;
#pragma unroll
        for (int off = 32; off; off >>= 1) ll += __shfl_xor(ll, off);
        l = ll;
        int j = 0;
        for (; j + 1 < cnt; j += 2) {
            int s0 = __shfl(s_l, j), s1 = __shfl(s_l, j + 1);
            float e0 = __shfl(ev_l, j), e1 = __shfl(ev_l, j + 1);
            acc0 += e0 * hs[(size_t)s0 * H + lane];
            acc1 += e1 * hs[(size_t)s1 * H + lane];
        }
        if (j < cnt) acc0 += __shfl(ev_l, j) * hs[(size_t)__shfl(s_l, j) * H + lane];
    } else {
        // general path: separate max pass then accumulate pass
        float mm = -3.4e38f;
        for (int base = beg; base < end; base += 64) {
            int idx = base + lane;
            if (idx < end) {
                float sc = ssrc[srcs[idx]] + sdst;
                sc = sc > 0.f ? sc : 0.2f * sc;
                mm = fmaxf(mm, sc);
            }
        }
#pragma unroll
        for (int off = 32; off; off >>= 1) mm = fmaxf(mm, __shfl_xor(mm, off));
        float ll = 0.f;
        for (int base = beg; base < end; base += 64) {
            int idx = base + lane;
            int c2 = end - base; if (c2 > 64) c2 = 64;
            int s_l = idx < end ? srcs[idx] : 0;
            float ev_l = 0.f;
            if (idx < end) {
                float sc = ssrc[s_l] + sdst;
                sc = sc > 0.f ? sc : 0.2f * sc;
                ev_l = __expf(sc - mm);
            }
            ll += ev_l;
            for (int j = 0; j < c2; ++j) {
                int s = __shfl(s_l, j);
                float ev = __shfl(ev_l, j);
                acc0 += ev * hs[(size_t)s * H + lane];
            }
        }
#pragma unroll
        for (int off = 32; off; off >>= 1) ll += __shfl_xor(ll, off);
        l = ll;
    }
    float v = (acc0 + acc1) / (l + 1e-16f) + bias[lane];
    return v > 0.f ? v : 0.f;
}

__global__ void gat_node_kernel(const int* __restrict__ rowptr, const int* __restrict__ srcs,
                                const float* __restrict__ ssrc, const float* __restrict__ xdst,
                                const float* __restrict__ v2, const float* __restrict__ hs,
                                const float* __restrict__ bias, float* __restrict__ out, int ndst) {
    int wid = (int)((blockIdx.x * blockDim.x + threadIdx.x) >> 6);
    int lane = threadIdx.x & 63;
    if (wid >= ndst) return;
    out[(size_t)wid * H + lane] = gat_aggregate(rowptr, srcs, ssrc, xdst, v2, hs, bias, wid, lane);
}

// final relation: GAT aggregation + fused MLP head (half-wave split lin1)
__global__ void gat_node_mlp_kernel(const int* __restrict__ rowptr, const int* __restrict__ srcs,
                                    const float* __restrict__ ssrc, const float* __restrict__ xdst,
                                    const float* __restrict__ v2, const float* __restrict__ hs,
                                    const float* __restrict__ bias,
                                    const float* __restrict__ w1, const float* __restrict__ b1,
                                    const float* __restrict__ w2, const float* __restrict__ b2,
                                    float* __restrict__ out, int ndst) {
    __shared__ float W1[H * 32];
    __shared__ float W2[32];
    __shared__ float B1[32];
    {
        int t = threadIdx.x;
        for (int i = t; i < H * 32; i += 256) W1[i] = w1[i];
        if (t < 32) { W2[t] = w2[t]; B1[t] = b1[t]; }
        __syncthreads();
    }
    int wid = (int)((blockIdx.x * blockDim.x + threadIdx.x) >> 6);
    int lane = threadIdx.x & 63;
    if (wid >= ndst) return;
    float v = gat_aggregate(rowptr, srcs, ssrc, xdst, v2, hs, bias, wid, lane);

    // lin1: lanes 0..31 accumulate k=0..31, lanes 32..63 accumulate k=32..63
    int c = lane & 31;
    int kbase = (lane >> 5) << 5;
    float s = 0.f;
#pragma unroll
    for (int k = 0; k < 32; ++k) s += __shfl(v, kbase + k) * W1[(kbase + k) * 32 + c];
    s += __shfl_xor(s, 32);   // combine the two half-sums -> full h[c] in all lanes
    s += B1[c];
    s = s > 0.f ? s : 0.f;
    float q = s * W2[c];
#pragma unroll
    for (int off = 16; off; off >>= 1) q += __shfl_xor(q, off);
    if (lane == 0) out[wid] = q + b2[0];
}

extern "C" void kernel_launch(void* const* d_in, const int* in_sizes, int n_in,
                              void* d_out, int out_size, void* d_ws, size_t ws_size,
                              hipStream_t stream) {
    const float* x_inst  = (const float*)d_in[0];
    const float* x_net   = (const float*)d_in[1];
    const int*   e_i2n   = (const int*)d_in[2];
    const int*   e_n2i   = (const int*)d_in[3];
    const float* W_src   = (const float*)d_in[4];
    const float* W_dst   = (const float*)d_in[5];
    const float* att_src = (const float*)d_in[6];
    const float* att_dst = (const float*)d_in[7];
    const float* bias_g  = (const float*)d_in[8];
    const float* lin1_w  = (const float*)d_in[9];
    const float* lin1_b  = (const float*)d_in[10];
    const float* lin2_w  = (const float*)d_in[11];
    const float* lin2_b  = (const float*)d_in[12];

    const int n_inst = in_sizes[0] / H;
    const int n_net  = in_sizes[1] / H;
    const int ne     = in_sizes[2] / 2;
    const int nmax   = n_inst > n_net ? n_inst : n_net;

    float* ws = (float*)d_ws;
    size_t off = 0;
    auto alloc = [&](size_t nelem) { float* p = ws + off; off += nelem; return p; };
    float* xnA     = alloc((size_t)n_net * H);
    float* xiA     = alloc((size_t)n_inst * H);
    float* hs      = alloc((size_t)nmax * H);
    float* ssrc    = alloc(nmax);
    int*   rp_i2n  = (int*)alloc(nmax + 1);
    int*   sr_i2n  = (int*)alloc(ne);
    int*   rp_n2i  = (int*)alloc(nmax + 1);
    int*   sr_n2i  = (int*)alloc(ne);
    int*   cur1    = (int*)alloc(nmax);   // cursor/count for i2n (dst = net)
    int*   cur2    = (int*)alloc(nmax);   // cursor/count for n2i (dst = inst)
    int*   bsum    = (int*)alloc(1024);
    float* v2      = alloc(H);
    (void)ws_size;

    // ---- build both CSRs (shared across layers) ----
    fill_zero<<<256, 256, 0, stream>>>((float*)cur1, nmax);
    fill_zero<<<256, 256, 0, stream>>>((float*)cur2, nmax);
    hist2_kernel<<<4096, 256, 0, stream>>>(e_i2n + ne, e_n2i + ne, cur1, cur2, ne);
    {
        int nb1 = (n_net + 255) / 256;
        scan_block<<<nb1, 256, 0, stream>>>(cur1, rp_i2n, bsum, n_net);
        scan_bsum<<<1, 1024, 0, stream>>>(bsum, nb1);
        add_offsets<<<(n_net + 256) / 256, 256, 0, stream>>>(rp_i2n, bsum, cur1, n_net, ne);
        int nb2 = (n_inst + 255) / 256;
        scan_block<<<nb2, 256, 0, stream>>>(cur2, rp_n2i, bsum, n_inst);
        scan_bsum<<<1, 1024, 0, stream>>>(bsum, nb2);
        add_offsets<<<(n_inst + 256) / 256, 256, 0, stream>>>(rp_n2i, bsum, cur2, n_inst, ne);
    }
    scatter2_kernel<<<4096, 256, 0, stream>>>(e_i2n, e_i2n + ne, cur1, sr_i2n,
                                              e_n2i, e_n2i + ne, cur2, sr_n2i, ne);

    auto proj = [&](const float* xsrc, int nsrc, int li, int ri) {
        const float* Ws  = W_src + (size_t)(li * 2 + ri) * H * H;
        const float* Wd  = W_dst + (size_t)(li * 2 + ri) * H * H;
        const float* as_ = att_src + (size_t)(li * 2 + ri) * H;
        const float* ad_ = att_dst + (size_t)(li * 2 + ri) * H;
        wvec_kernel<<<1, 64, 0, stream>>>(Wd, ad_, v2);
        gemm_hs_fused<<<(nsrc + 3) / 4, 256, 0, stream>>>(xsrc, Ws, as_, hs, ssrc, nsrc);
    };

    // layer 0, relation 0: inst -> net
    proj(x_inst, n_inst, 0, 0);
    gat_node_kernel<<<(n_net + 3) / 4, 256, 0, stream>>>(rp_i2n, sr_i2n, ssrc, x_net, v2,
                                                         hs, bias_g + 0 * H, xnA, n_net);
    // layer 0, relation 1: net -> inst
    proj(x_net, n_net, 0, 1);
    gat_node_kernel<<<(n_inst + 3) / 4, 256, 0, stream>>>(rp_n2i, sr_n2i, ssrc, x_inst, v2,
                                                          hs, bias_g + 1 * H, xiA, n_inst);
    // layer 1, relation 0: inst -> net, fused with MLP head (inst-side l1 is dead)
    proj(xiA, n_inst, 1, 0);
    gat_node_mlp_kernel<<<(n_net + 3) / 4, 256, 0, stream>>>(rp_i2n, sr_i2n, ssrc, xnA, v2,
                                                             hs, bias_g + 2 * H,
                                                             lin1_w, lin1_b, lin2_w, lin2_b,
                                                             (float*)d_out, n_net);
}